// Round 1
// baseline (193.343 us; speedup 1.0000x reference)
//
#include <hip/hip_runtime.h>
#include <hip/hip_bf16.h>
#include <math.h>

typedef _Float16 half8 __attribute__((ext_vector_type(8)));
typedef float f32x4 __attribute__((ext_vector_type(4)));

#define BATCH 100
#define CH    512
#define HWP   256
#define SAMP  (CH * HWP)   // 131072 elems per sample

// ---- async global->LDS 16B (wave-uniform LDS base + lane*16) ----
__device__ __forceinline__ void async16(const void* g, void* l) {
  __builtin_amdgcn_global_load_lds(
      (const __attribute__((address_space(1))) unsigned int*)g,
      (__attribute__((address_space(3))) unsigned int*)l, 16, 0, 0);
}

// ---- K0a: transpose + fp32->fp16:  x[b][c][p] -> xh[b][p][c] ----
__global__ __launch_bounds__(256) void k_txpose(const float* __restrict__ x,
                                               _Float16* __restrict__ xh) {
  __shared__ _Float16 tbuf[32][33];
  int bid  = blockIdx.x;
  int b    = bid >> 7;          // /128 tiles per batch
  int tile = bid & 127;
  int c0 = (tile >> 3) << 5;    // 16 c-tiles
  int p0 = (tile & 7) << 5;     // 8 p-tiles
  int tx = threadIdx.x & 31;
  int ty = threadIdx.x >> 5;    // 0..7
  const float* xb = x + (size_t)b * SAMP;
#pragma unroll
  for (int i = 0; i < 4; i++) {
    int c = ty + i * 8;
    tbuf[c][tx] = (_Float16)xb[(size_t)(c0 + c) * HWP + p0 + tx];
  }
  __syncthreads();
  _Float16* xhb = xh + (size_t)b * SAMP;
#pragma unroll
  for (int i = 0; i < 4; i++) {
    int p = ty + i * 8;
    xhb[(size_t)(p0 + p) * CH + c0 + tx] = tbuf[tx][p];
  }
}

// ---- K0b: W fp32->fp16 ----
__global__ __launch_bounds__(256) void k_convw(const float* __restrict__ W,
                                              _Float16* __restrict__ Wh) {
  int base = blockIdx.x * 1024 + threadIdx.x;
#pragma unroll
  for (int j = 0; j < 4; j++) Wh[base + j * 256] = (_Float16)W[base + j * 256];
}

// ---- K1: batched GEMM  logit[b][o][p] = sum_c W[o][c] * x[b][c][p] + bias[o]
// A = Wh (o,c) row-major; B^T = xh[b] (p,c) row-major. 128x128 tile, BK=32.
__global__ __launch_bounds__(256) void k_gemm(const _Float16* __restrict__ Wh,
                                             const _Float16* __restrict__ xh,
                                             const float* __restrict__ bias,
                                             float* __restrict__ logits) {
  __shared__ __align__(16) _Float16 As[128 * 32];
  __shared__ __align__(16) _Float16 Bs[128 * 32];
  int bid   = blockIdx.x;
  int batch = bid >> 3;
  int sub   = bid & 7;
  int ot = sub & 3, pt = sub >> 2;     // o-tile fastest: 4 o-tiles share one x-tile in L2
  int o0 = ot * 128, p0 = pt * 128;
  const _Float16* Bg = xh + (size_t)batch * SAMP;   // [p][c] 256x512

  int t  = threadIdx.x;
  int wv = t >> 6, ln = t & 63;
  int qd = ln >> 4, r = ln & 15;
  int wm0 = (wv >> 1) * 64, wn0 = (wv & 1) * 64;

  f32x4 acc[4][4] = {};

  for (int kk = 0; kk < 512; kk += 32) {
#pragma unroll
    for (int it = 0; it < 2; it++) {
      int ch  = it * 256 + t;         // 0..511 chunks of 16B
      int row = ch >> 2;              // 0..127
      int qc  = ch & 3;               // 4 chunks per 64B row
      char* la = (char*)As + (size_t)(it * 256 + wv * 64) * 16;   // wave-uniform
      char* lb = (char*)Bs + (size_t)(it * 256 + wv * 64) * 16;
      async16((const char*)(Wh + (size_t)(o0 + row) * 512 + kk + qc * 8), la);
      async16((const char*)(Bg + (size_t)(p0 + row) * 512 + kk + qc * 8), lb);
    }
    __syncthreads();
    half8 af[4], bf[4];
#pragma unroll
    for (int i = 0; i < 4; i++)
      af[i] = *(const half8*)(As + (wm0 + i * 16 + r) * 32 + qd * 8);
#pragma unroll
    for (int j = 0; j < 4; j++)
      bf[j] = *(const half8*)(Bs + (wn0 + j * 16 + r) * 32 + qd * 8);
#pragma unroll
    for (int i = 0; i < 4; i++)
#pragma unroll
      for (int j = 0; j < 4; j++)
        acc[i][j] = __builtin_amdgcn_mfma_f32_16x16x32_f16(af[i], bf[j], acc[i][j], 0, 0, 0);
    __syncthreads();
  }

  float* outb = logits + (size_t)batch * SAMP;    // [o][p]
#pragma unroll
  for (int i = 0; i < 4; i++) {
#pragma unroll
    for (int rg = 0; rg < 4; rg++) {
      int o = o0 + wm0 + i * 16 + qd * 4 + rg;
      float bv = bias[o];
#pragma unroll
      for (int j = 0; j < 4; j++) {
        int p = p0 + wn0 + j * 16 + r;
        outb[(size_t)o * HWP + p] = acc[i][j][rg] + bv;
      }
    }
  }
}

// ---- K2: denom[b] = sum over 131072 of exp(logit). (|logit|<~10 -> no max pass needed)
__global__ __launch_bounds__(256) void k_denom(const float* __restrict__ logits,
                                              float* __restrict__ denom) {
  int b = blockIdx.x >> 3, s = blockIdx.x & 7;
  const float4* base = (const float4*)(logits + (size_t)b * SAMP + s * 16384);
  int t = threadIdx.x;
  float acc = 0.f;
#pragma unroll
  for (int i = 0; i < 16; i++) {
    float4 v = base[i * 256 + t];
    acc += expf(v.x) + expf(v.y) + expf(v.z) + expf(v.w);
  }
#pragma unroll
  for (int off = 32; off; off >>= 1) acc += __shfl_down(acc, off, 64);
  __shared__ float rs[4];
  if ((t & 63) == 0) rs[t >> 6] = acc;
  __syncthreads();
  if (t == 0) atomicAdd(&denom[b], rs[0] + rs[1] + rs[2] + rs[3]);
}

// ---- K3: prototypes s[m][c] = mean over 5 shots x 256 positions of y ----
__global__ __launch_bounds__(256) void k_proto(const float* __restrict__ x,
                                              const float* __restrict__ logits,
                                              const float* __restrict__ denom,
                                              float* __restrict__ sproto) {
  int m = blockIdx.x / 512, c = blockIdx.x % 512;
  int t = threadIdx.x;
  float acc = 0.f;
  for (int j = 0; j < 5; j++) {
    int b = m * 20 + j;
    float invd = 1.0f / denom[b];
    size_t idx = (size_t)b * SAMP + (size_t)c * HWP + t;
    acc += x[idx] * expf(logits[idx]) * invd;
  }
#pragma unroll
  for (int off = 32; off; off >>= 1) acc += __shfl_down(acc, off, 64);
  __shared__ float rs[4];
  if ((t & 63) == 0) rs[t >> 6] = acc;
  __syncthreads();
  if (t == 0) sproto[m * 512 + c] = (rs[0] + rs[1] + rs[2] + rs[3]) * (1.0f / 1280.0f);
}

// ---- K3b: pref[m] = SCALE / max(||s[m]||, eps) ----
__global__ __launch_bounds__(256) void k_sn(const float* __restrict__ sproto,
                                           float* __restrict__ pref) {
  int m = blockIdx.x, t = threadIdx.x;
  float v1 = sproto[m * 512 + t], v2 = sproto[m * 512 + 256 + t];
  float acc = v1 * v1 + v2 * v2;
#pragma unroll
  for (int off = 32; off; off >>= 1) acc += __shfl_down(acc, off, 64);
  __shared__ float rs[4];
  if ((t & 63) == 0) rs[t >> 6] = acc;
  __syncthreads();
  if (t == 0) {
    float sn = fmaxf(sqrtf(rs[0] + rs[1] + rs[2] + rs[3]), 1e-8f);
    pref[m] = 10.0f / sn;
  }
}

// ---- K4: per query n, per position f: cosine scores -> softmax(5) -> mean over f
__global__ __launch_bounds__(1024) void k_scores(const float* __restrict__ x,
                                                const float* __restrict__ logits,
                                                const float* __restrict__ denom,
                                                const float* __restrict__ sproto,
                                                const float* __restrict__ pref,
                                                float* __restrict__ out) {
  __shared__ float s_lds[5 * 512];
  __shared__ float red[1024 * 6];
  __shared__ float pm[5 * 256];
  int n = blockIdx.x;
  int b = (n / 15) * 20 + 5 + (n % 15);
  int t = threadIdx.x, f = t & 255, g = t >> 8;   // g: c-split 0..3
  for (int i = t; i < 2560; i += 1024) s_lds[i] = sproto[i];
  __syncthreads();
  float invd = 1.0f / denom[b];
  const float* xb = x + (size_t)b * SAMP;
  const float* lb = logits + (size_t)b * SAMP;
  float dot[5] = {0, 0, 0, 0, 0}, qq = 0.f;
  for (int c = g * 128; c < g * 128 + 128; c++) {
    float v = xb[(size_t)c * HWP + f] * expf(lb[(size_t)c * HWP + f]) * invd;
    qq += v * v;
#pragma unroll
    for (int m = 0; m < 5; m++) dot[m] += v * s_lds[m * 512 + c];
  }
#pragma unroll
  for (int m = 0; m < 5; m++) red[t * 6 + m] = dot[m];
  red[t * 6 + 5] = qq;
  __syncthreads();
  if (g == 0) {
#pragma unroll
    for (int gg = 1; gg < 4; gg++) {
#pragma unroll
      for (int m = 0; m < 5; m++) dot[m] += red[(t + gg * 256) * 6 + m];
      qq += red[(t + gg * 256) * 6 + 5];
    }
    float iqn = 1.0f / fmaxf(sqrtf(qq), 1e-8f);
    float sc[5], mx = -1e30f;
#pragma unroll
    for (int m = 0; m < 5; m++) { sc[m] = dot[m] * pref[m] * iqn; mx = fmaxf(mx, sc[m]); }
    float p[5], ssum = 0.f;
#pragma unroll
    for (int m = 0; m < 5; m++) { p[m] = expf(sc[m] - mx); ssum += p[m]; }
    float rr = 1.0f / ssum;
#pragma unroll
    for (int m = 0; m < 5; m++) pm[m * 256 + f] = p[m] * rr;
  }
  for (int s = 128; s > 0; s >>= 1) {
    __syncthreads();
    if (g == 0 && f < s) {
#pragma unroll
      for (int m = 0; m < 5; m++) pm[m * 256 + f] += pm[m * 256 + f + s];
    }
  }
  __syncthreads();
  if (t < 5) out[n * 5 + t] = pm[t * 256] * (1.0f / 256.0f);
}

extern "C" void kernel_launch(void* const* d_in, const int* in_sizes, int n_in,
                              void* d_out, int out_size, void* d_ws, size_t ws_size,
                              hipStream_t stream) {
  const float* x    = (const float*)d_in[0];   // (100,512,16,16)
  const float* W    = (const float*)d_in[1];   // (512,512)
  const float* bias = (const float*)d_in[2];   // (512,)
  float* out = (float*)d_out;                  // (75,5) fp32

  char* ws = (char*)d_ws;
  _Float16* xh     = (_Float16*)(ws + 0);          // 26,214,400 B
  _Float16* Wh     = (_Float16*)(ws + 26214400);   //    524,288 B
  float*    logits = (float*)   (ws + 26738688);   // 52,428,800 B
  float*    denom  = (float*)   (ws + 79167488);   //        400 B (pad 512)
  float*    sproto = (float*)   (ws + 79168000);   //     10,240 B
  float*    pref   = (float*)   (ws + 79178240);   //         20 B

  hipMemsetAsync(denom, 0, 512, stream);
  k_txpose <<<12800, 256, 0, stream>>>(x, xh);
  k_convw  <<<256,   256, 0, stream>>>(W, Wh);
  k_gemm   <<<800,   256, 0, stream>>>(Wh, xh, bias, logits);
  k_denom  <<<800,   256, 0, stream>>>(logits, denom);
  k_proto  <<<2560,  256, 0, stream>>>(x, logits, denom, sproto);
  k_sn     <<<5,     256, 0, stream>>>(sproto, pref);
  k_scores <<<75,   1024, 0, stream>>>(x, logits, denom, sproto, pref, out);
}

// Round 2
// 152.821 us; speedup vs baseline: 1.2652x; 1.2652x over previous
//
#include <hip/hip_runtime.h>
#include <hip/hip_bf16.h>
#include <math.h>

typedef _Float16 half8 __attribute__((ext_vector_type(8)));
typedef float f32x4 __attribute__((ext_vector_type(4)));

#define BATCH 100
#define CH    512
#define HWP   256
#define SAMP  (CH * HWP)   // 131072 elems per sample

// ---- async global->LDS 16B (wave-uniform LDS base + lane*16) ----
__device__ __forceinline__ void async16(const void* g, void* l) {
  __builtin_amdgcn_global_load_lds(
      (const __attribute__((address_space(1))) unsigned int*)g,
      (__attribute__((address_space(3))) unsigned int*)l, 16, 0, 0);
}

// ---- K0a: transpose + fp32->fp16:  x[b][c][p] -> xh[b][p][c]
// 64c x 64p tile per block; LDS fp32 [64][69] (pad 5 -> max 2-way bank alias = free).
// Global reads 16B-chunk coalesced, global writes half8 (16B/lane).
__global__ __launch_bounds__(256) void k_txpose(const float* __restrict__ x,
                                               _Float16* __restrict__ xh) {
  __shared__ float tb[64][69];
  int bid  = blockIdx.x;
  int b    = bid >> 5;          // 32 tiles per batch
  int tile = bid & 31;
  int c0 = (tile >> 2) << 6;    // 8 c-tiles of 64
  int p0 = (tile & 3) << 6;     // 4 p-tiles of 64
  int t = threadIdx.x;
  const float* xb = x + (size_t)b * SAMP;
#pragma unroll
  for (int it = 0; it < 4; it++) {
    int ch = it * 256 + t;
    int c  = ch >> 4;           // 0..63
    int pc = (ch & 15) << 2;    // 0..60
    float4 v = *(const float4*)(xb + (size_t)(c0 + c) * HWP + p0 + pc);
    tb[c][pc] = v.x; tb[c][pc + 1] = v.y; tb[c][pc + 2] = v.z; tb[c][pc + 3] = v.w;
  }
  __syncthreads();
  _Float16* xhb = xh + (size_t)b * SAMP;
#pragma unroll
  for (int it = 0; it < 2; it++) {
    int ch = it * 256 + t;
    int p  = ch >> 3;           // 0..63
    int ck = (ch & 7) << 3;     // 0..56
    half8 h;
#pragma unroll
    for (int j = 0; j < 8; j++) h[j] = (_Float16)tb[ck + j][p];
    *(half8*)(xhb + (size_t)(p0 + p) * CH + c0 + ck) = h;
  }
}

// ---- K0b: W fp32->fp16 ----
__global__ __launch_bounds__(256) void k_convw(const float* __restrict__ W,
                                              _Float16* __restrict__ Wh) {
  int base = blockIdx.x * 1024 + threadIdx.x;
#pragma unroll
  for (int j = 0; j < 4; j++) Wh[base + j * 256] = (_Float16)W[base + j * 256];
}

// ---- K1: batched GEMM + fused exp + denom partial-sum.
// e[b][o][p] = exp( sum_c W[o][c]*x[b][c][p] + bias[o] );  denom[b] += block partial
// A = Wh (o,c) row-major; B^T = xh[b] (p,c) row-major. 128x128 tile, BK=32.
__global__ __launch_bounds__(256) void k_gemm(const _Float16* __restrict__ Wh,
                                             const _Float16* __restrict__ xh,
                                             const float* __restrict__ bias,
                                             float* __restrict__ eout,
                                             float* __restrict__ denom) {
  __shared__ __align__(16) _Float16 As[128 * 32];
  __shared__ __align__(16) _Float16 Bs[128 * 32];
  int bid   = blockIdx.x;
  int batch = bid >> 3;
  int sub   = bid & 7;
  int ot = sub & 3, pt = sub >> 2;     // o-tile fastest: 4 o-tiles share one x-tile in L2
  int o0 = ot * 128, p0 = pt * 128;
  const _Float16* Bg = xh + (size_t)batch * SAMP;   // [p][c] 256x512

  int t  = threadIdx.x;
  int wv = t >> 6, ln = t & 63;
  int qd = ln >> 4, r = ln & 15;
  int wm0 = (wv >> 1) * 64, wn0 = (wv & 1) * 64;

  f32x4 acc[4][4] = {};

  for (int kk = 0; kk < 512; kk += 32) {
#pragma unroll
    for (int it = 0; it < 2; it++) {
      int ch  = it * 256 + t;         // 0..511 chunks of 16B
      int row = ch >> 2;              // 0..127
      int qc  = ch & 3;               // 4 chunks per 64B row
      char* la = (char*)As + (size_t)(it * 256 + wv * 64) * 16;   // wave-uniform
      char* lb = (char*)Bs + (size_t)(it * 256 + wv * 64) * 16;
      async16((const char*)(Wh + (size_t)(o0 + row) * 512 + kk + qc * 8), la);
      async16((const char*)(Bg + (size_t)(p0 + row) * 512 + kk + qc * 8), lb);
    }
    __syncthreads();
    half8 af[4], bf[4];
#pragma unroll
    for (int i = 0; i < 4; i++)
      af[i] = *(const half8*)(As + (wm0 + i * 16 + r) * 32 + qd * 8);
#pragma unroll
    for (int j = 0; j < 4; j++)
      bf[j] = *(const half8*)(Bs + (wn0 + j * 16 + r) * 32 + qd * 8);
#pragma unroll
    for (int i = 0; i < 4; i++)
#pragma unroll
      for (int j = 0; j < 4; j++)
        acc[i][j] = __builtin_amdgcn_mfma_f32_16x16x32_f16(af[i], bf[j], acc[i][j], 0, 0, 0);
    __syncthreads();
  }

  float* outb = eout + (size_t)batch * SAMP;    // [o][p]
  float lsum = 0.f;
#pragma unroll
  for (int i = 0; i < 4; i++) {
#pragma unroll
    for (int rg = 0; rg < 4; rg++) {
      int o = o0 + wm0 + i * 16 + qd * 4 + rg;
      float bv = bias[o];
#pragma unroll
      for (int j = 0; j < 4; j++) {
        int p = p0 + wn0 + j * 16 + r;
        float e = __expf(acc[i][j][rg] + bv);
        outb[(size_t)o * HWP + p] = e;
        lsum += e;
      }
    }
  }
#pragma unroll
  for (int off = 32; off; off >>= 1) lsum += __shfl_down(lsum, off, 64);
  __shared__ float rs[4];
  if (ln == 0) rs[wv] = lsum;
  __syncthreads();
  if (t == 0) atomicAdd(&denom[batch], rs[0] + rs[1] + rs[2] + rs[3]);
}

// ---- K3: prototypes s[m][c] = mean over 5 shots x 256 positions of x*e/denom ----
__global__ __launch_bounds__(256) void k_proto(const float* __restrict__ x,
                                              const float* __restrict__ e,
                                              const float* __restrict__ denom,
                                              float* __restrict__ sproto) {
  int m = blockIdx.x / 512, c = blockIdx.x % 512;
  int t = threadIdx.x;
  float acc = 0.f;
  for (int j = 0; j < 5; j++) {
    int b = m * 20 + j;
    float invd = 1.0f / denom[b];
    size_t idx = (size_t)b * SAMP + (size_t)c * HWP + t;
    acc += x[idx] * e[idx] * invd;
  }
#pragma unroll
  for (int off = 32; off; off >>= 1) acc += __shfl_down(acc, off, 64);
  __shared__ float rs[4];
  if ((t & 63) == 0) rs[t >> 6] = acc;
  __syncthreads();
  if (t == 0) sproto[m * 512 + c] = (rs[0] + rs[1] + rs[2] + rs[3]) * (1.0f / 1280.0f);
}

// ---- K3b: pref[m] = SCALE / max(||s[m]||, eps) ----
__global__ __launch_bounds__(256) void k_sn(const float* __restrict__ sproto,
                                           float* __restrict__ pref) {
  int m = blockIdx.x, t = threadIdx.x;
  float v1 = sproto[m * 512 + t], v2 = sproto[m * 512 + 256 + t];
  float acc = v1 * v1 + v2 * v2;
#pragma unroll
  for (int off = 32; off; off >>= 1) acc += __shfl_down(acc, off, 64);
  __shared__ float rs[4];
  if ((t & 63) == 0) rs[t >> 6] = acc;
  __syncthreads();
  if (t == 0) {
    float sn = fmaxf(sqrtf(rs[0] + rs[1] + rs[2] + rs[3]), 1e-8f);
    pref[m] = 10.0f / sn;
  }
}

// ---- K4a: per (query n, c-chunk gc): partial dots + qq over 32 channels.
// NOTE: invd cancels in cosine similarity (common scale on the query) -> use u = x*e.
__global__ __launch_bounds__(256) void k_part(const float* __restrict__ x,
                                             const float* __restrict__ e,
                                             const float* __restrict__ sproto,
                                             float* __restrict__ part) {
  __shared__ float s_l[5 * 32];
  int n = blockIdx.x >> 4, gc = blockIdx.x & 15;
  int b = (n / 15) * 20 + 5 + (n % 15);
  int t = threadIdx.x;                // position f
  int c0 = gc * 32;
  if (t < 160) s_l[t] = sproto[(t / 32) * 512 + c0 + (t % 32)];
  __syncthreads();
  const float* xb = x + (size_t)b * SAMP + (size_t)c0 * HWP;
  const float* eb = e + (size_t)b * SAMP + (size_t)c0 * HWP;
  float dot[5] = {0, 0, 0, 0, 0}, qq = 0.f;
#pragma unroll 8
  for (int c = 0; c < 32; c++) {
    float u = xb[c * HWP + t] * eb[c * HWP + t];
    qq += u * u;
#pragma unroll
    for (int m = 0; m < 5; m++) dot[m] += u * s_l[m * 32 + c];
  }
  float* pp = part + (((size_t)n * 16 + gc) * 256 + t) * 6;
  pp[0] = dot[0]; pp[1] = dot[1]; pp[2] = dot[2];
  pp[3] = dot[3]; pp[4] = dot[4]; pp[5] = qq;
}

// ---- K4b: combine partials -> cosine -> softmax(5) -> spatial mean ----
__global__ __launch_bounds__(256) void k_comb(const float* __restrict__ part,
                                             const float* __restrict__ pref,
                                             float* __restrict__ out) {
  int n = blockIdx.x, t = threadIdx.x;   // t = position f
  float dot[5] = {0, 0, 0, 0, 0}, qq = 0.f;
#pragma unroll
  for (int gc = 0; gc < 16; gc++) {
    const float* pp = part + (((size_t)n * 16 + gc) * 256 + t) * 6;
    dot[0] += pp[0]; dot[1] += pp[1]; dot[2] += pp[2];
    dot[3] += pp[3]; dot[4] += pp[4]; qq += pp[5];
  }
  float iqn = 1.0f / fmaxf(sqrtf(qq), 1e-20f);   // clamp mathematically inactive
  float sc[5], mx = -1e30f;
#pragma unroll
  for (int m = 0; m < 5; m++) { sc[m] = dot[m] * pref[m] * iqn; mx = fmaxf(mx, sc[m]); }
  float p[5], ssum = 0.f;
#pragma unroll
  for (int m = 0; m < 5; m++) { p[m] = __expf(sc[m] - mx); ssum += p[m]; }
  float rr = 1.0f / ssum;
#pragma unroll
  for (int m = 0; m < 5; m++) {
    float v = p[m] * rr;
#pragma unroll
    for (int off = 32; off; off >>= 1) v += __shfl_down(v, off, 64);
    p[m] = v;   // lane0 of each wave holds wave sum
  }
  __shared__ float rs[4][5];
  if ((t & 63) == 0) {
#pragma unroll
    for (int m = 0; m < 5; m++) rs[t >> 6][m] = p[m];
  }
  __syncthreads();
  if (t < 5) out[n * 5 + t] =
      (rs[0][t] + rs[1][t] + rs[2][t] + rs[3][t]) * (1.0f / 256.0f);
}

extern "C" void kernel_launch(void* const* d_in, const int* in_sizes, int n_in,
                              void* d_out, int out_size, void* d_ws, size_t ws_size,
                              hipStream_t stream) {
  const float* x    = (const float*)d_in[0];   // (100,512,16,16)
  const float* W    = (const float*)d_in[1];   // (512,512)
  const float* bias = (const float*)d_in[2];   // (512,)
  float* out = (float*)d_out;                  // (75,5) fp32

  char* ws = (char*)d_ws;
  _Float16* xh     = (_Float16*)(ws + 0);          // 26,214,400 B (dead after gemm)
  float*    part   = (float*)   (ws + 0);          //  7,372,800 B (aliases xh)
  _Float16* Wh     = (_Float16*)(ws + 26214400);   //    524,288 B
  float*    e      = (float*)   (ws + 26738688);   // 52,428,800 B  exp(logits)
  float*    denom  = (float*)   (ws + 79167488);   //        512 B
  float*    sproto = (float*)   (ws + 79168000);   //     10,240 B
  float*    pref   = (float*)   (ws + 79178240);   //        512 B

  hipMemsetAsync(denom, 0, 512, stream);
  k_txpose <<<3200, 256, 0, stream>>>(x, xh);
  k_convw  <<<256,  256, 0, stream>>>(W, Wh);
  k_gemm   <<<800,  256, 0, stream>>>(Wh, xh, bias, e, denom);
  k_proto  <<<2560, 256, 0, stream>>>(x, e, denom, sproto);
  k_sn     <<<5,    256, 0, stream>>>(sproto, pref);
  k_part   <<<1200, 256, 0, stream>>>(x, e, sproto, part);
  k_comb   <<<75,   256, 0, stream>>>(part, pref, out);
}

// Round 4
// 142.109 us; speedup vs baseline: 1.3605x; 1.0754x over previous
//
#include <hip/hip_runtime.h>
#include <hip/hip_bf16.h>
#include <math.h>

typedef _Float16 half8 __attribute__((ext_vector_type(8)));
typedef float f32x4 __attribute__((ext_vector_type(4)));

#define BATCH 100
#define CH    512
#define HWP   256
#define SAMP  (CH * HWP)   // 131072 elems per sample

// ---- async global->LDS 16B (wave-uniform LDS base + lane*16) ----
__device__ __forceinline__ void async16(const void* g, void* l) {
  __builtin_amdgcn_global_load_lds(
      (const __attribute__((address_space(1))) unsigned int*)g,
      (__attribute__((address_space(3))) unsigned int*)l, 16, 0, 0);
}

// ---- K0a: transpose + fp32->fp16:  x[b][c][p] -> xh[b][p][c]
// 64c x 64p tile per block; LDS fp32 [64][69] (pad 5 -> max 2-way bank alias = free).
__global__ __launch_bounds__(256) void k_txpose(const float* __restrict__ x,
                                               _Float16* __restrict__ xh) {
  __shared__ float tb[64][69];
  int bid  = blockIdx.x;
  int b    = bid >> 5;          // 32 tiles per batch
  int tile = bid & 31;
  int c0 = (tile >> 2) << 6;    // 8 c-tiles of 64
  int p0 = (tile & 3) << 6;     // 4 p-tiles of 64
  int t = threadIdx.x;
  const float* xb = x + (size_t)b * SAMP;
#pragma unroll
  for (int it = 0; it < 4; it++) {
    int ch = it * 256 + t;
    int c  = ch >> 4;           // 0..63
    int pc = (ch & 15) << 2;    // 0..60
    float4 v = *(const float4*)(xb + (size_t)(c0 + c) * HWP + p0 + pc);
    tb[c][pc] = v.x; tb[c][pc + 1] = v.y; tb[c][pc + 2] = v.z; tb[c][pc + 3] = v.w;
  }
  __syncthreads();
  _Float16* xhb = xh + (size_t)b * SAMP;
#pragma unroll
  for (int it = 0; it < 2; it++) {
    int ch = it * 256 + t;
    int p  = ch >> 3;           // 0..63
    int ck = (ch & 7) << 3;     // 0..56
    half8 h;
#pragma unroll
    for (int j = 0; j < 8; j++) h[j] = (_Float16)tb[ck + j][p];
    *(half8*)(xhb + (size_t)(p0 + p) * CH + c0 + ck) = h;
  }
}

// ---- K0b: W fp32->fp16 ----
__global__ __launch_bounds__(256) void k_convw(const float* __restrict__ W,
                                              _Float16* __restrict__ Wh) {
  int base = blockIdx.x * 1024 + threadIdx.x;
#pragma unroll
  for (int j = 0; j < 4; j++) Wh[base + j * 256] = (_Float16)W[base + j * 256];
}

// ---- K1: batched GEMM + fused exp + denom partial + u = x*e (fp16) store.
// logit[b][o][p] = sum_c W[o][c]*x[b][c][p] + bias[o];  e = exp(logit)
// u[b][o][p] = x[b][o][p] * e   (invd applied later / cancels in cosine)
// A = Wh (o,c) row-major; B^T = xh[b] (p,c) row-major. 128x128 tile, BK=32.
__global__ __launch_bounds__(256) void k_gemm(const _Float16* __restrict__ Wh,
                                             const _Float16* __restrict__ xh,
                                             const float* __restrict__ bias,
                                             _Float16* __restrict__ u,
                                             float* __restrict__ denom) {
  // one buffer: K-loop uses [0:8192) halfs as As/Bs; epilogue reuses all
  // 17408 halfs as padded x-tile [128p][136c] (pad 8 -> <=2-way bank alias).
  __shared__ __align__(16) _Float16 smem[128 * 136];
  _Float16* As = smem;          // 128x32
  _Float16* Bs = smem + 4096;   // 128x32
  int bid   = blockIdx.x;
  int batch = bid >> 3;
  int sub   = bid & 7;
  int ot = sub & 3, pt = sub >> 2;     // o-tile fastest: 4 o-tiles share one x-tile in L2
  int o0 = ot * 128, p0 = pt * 128;
  const _Float16* Bg = xh + (size_t)batch * SAMP;   // [p][c] 256x512

  int t  = threadIdx.x;
  int wv = t >> 6, ln = t & 63;
  int qd = ln >> 4, r = ln & 15;
  int wm0 = (wv >> 1) * 64, wn0 = (wv & 1) * 64;

  f32x4 acc[4][4] = {};

  for (int kk = 0; kk < 512; kk += 32) {
#pragma unroll
    for (int it = 0; it < 2; it++) {
      int ch  = it * 256 + t;         // 0..511 chunks of 16B
      int row = ch >> 2;              // 0..127
      int qc  = ch & 3;               // 4 chunks per 64B row
      char* la = (char*)As + (size_t)(it * 256 + wv * 64) * 16;   // wave-uniform
      char* lb = (char*)Bs + (size_t)(it * 256 + wv * 64) * 16;
      async16((const char*)(Wh + (size_t)(o0 + row) * 512 + kk + qc * 8), la);
      async16((const char*)(Bg + (size_t)(p0 + row) * 512 + kk + qc * 8), lb);
    }
    __syncthreads();
    half8 af[4], bf[4];
#pragma unroll
    for (int i = 0; i < 4; i++)
      af[i] = *(const half8*)(As + (wm0 + i * 16 + r) * 32 + qd * 8);
#pragma unroll
    for (int j = 0; j < 4; j++)
      bf[j] = *(const half8*)(Bs + (wn0 + j * 16 + r) * 32 + qd * 8);
#pragma unroll
    for (int i = 0; i < 4; i++)
#pragma unroll
      for (int j = 0; j < 4; j++)
        acc[i][j] = __builtin_amdgcn_mfma_f32_16x16x32_f16(af[i], bf[j], acc[i][j], 0, 0, 0);
    __syncthreads();
  }

  // ---- epilogue: restage x-tile (from xh, [p][c] fp16, c-contig) into padded LDS
#pragma unroll
  for (int it = 0; it < 8; it++) {
    int ch = it * 256 + t;        // 0..2047 half8-chunks
    int p  = ch >> 4;             // 0..127
    int ck = ch & 15;             // *8 halfs
    half8 v = *(const half8*)(Bg + (size_t)(p0 + p) * CH + o0 + ck * 8);
    *(half8*)(smem + p * 136 + ck * 8) = v;
  }
  __syncthreads();

  _Float16* outb = u + (size_t)batch * SAMP;    // [o][p]
  float lsum = 0.f;
#pragma unroll
  for (int i = 0; i < 4; i++) {
#pragma unroll
    for (int rg = 0; rg < 4; rg++) {
      int ol = wm0 + i * 16 + qd * 4 + rg;      // local o (== mask channel)
      float bv = bias[o0 + ol];
#pragma unroll
      for (int j = 0; j < 4; j++) {
        int pl = wn0 + j * 16 + r;              // local p
        float ev = __expf(acc[i][j][rg] + bv);
        lsum += ev;
        float xv = (float)smem[pl * 136 + ol];
        outb[(size_t)(o0 + ol) * HWP + p0 + pl] = (_Float16)(xv * ev);
      }
    }
  }
#pragma unroll
  for (int off = 32; off; off >>= 1) lsum += __shfl_down(lsum, off, 64);
  __shared__ float rs[4];
  if (ln == 0) rs[wv] = lsum;
  __syncthreads();
  if (t == 0) atomicAdd(&denom[batch], rs[0] + rs[1] + rs[2] + rs[3]);
}

// ---- K3: prototypes s[m][c] = (1/1280) * sum_j invd_j * sum_p u ----
__global__ __launch_bounds__(256) void k_proto(const _Float16* __restrict__ u,
                                              const float* __restrict__ denom,
                                              float* __restrict__ sproto) {
  int m = blockIdx.x / 512, c = blockIdx.x % 512;
  int t = threadIdx.x;
  float acc = 0.f;
  for (int j = 0; j < 5; j++) {
    int b = m * 20 + j;
    float invd = 1.0f / denom[b];
    acc += (float)u[(size_t)b * SAMP + (size_t)c * HWP + t] * invd;
  }
#pragma unroll
  for (int off = 32; off; off >>= 1) acc += __shfl_down(acc, off, 64);
  __shared__ float rs[4];
  if ((t & 63) == 0) rs[t >> 6] = acc;
  __syncthreads();
  if (t == 0) sproto[m * 512 + c] = (rs[0] + rs[1] + rs[2] + rs[3]) * (1.0f / 1280.0f);
}

// ---- K3b: pref[m] = SCALE / max(||s[m]||, eps) ----
__global__ __launch_bounds__(256) void k_sn(const float* __restrict__ sproto,
                                           float* __restrict__ pref) {
  int m = blockIdx.x, t = threadIdx.x;
  float v1 = sproto[m * 512 + t], v2 = sproto[m * 512 + 256 + t];
  float acc = v1 * v1 + v2 * v2;
#pragma unroll
  for (int off = 32; off; off >>= 1) acc += __shfl_down(acc, off, 64);
  __shared__ float rs[4];
  if ((t & 63) == 0) rs[t >> 6] = acc;
  __syncthreads();
  if (t == 0) {
    float sn = fmaxf(sqrtf(rs[0] + rs[1] + rs[2] + rs[3]), 1e-8f);
    pref[m] = 10.0f / sn;
  }
}

// ---- K4a: per (query n, c-chunk gc of 64): partial dots + qq from u (fp16) ----
__global__ __launch_bounds__(256) void k_part(const _Float16* __restrict__ u,
                                             const float* __restrict__ sproto,
                                             float* __restrict__ part) {
  __shared__ float s_l[5 * 64];
  int n = blockIdx.x >> 3, gc = blockIdx.x & 7;
  int b = (n / 15) * 20 + 5 + (n % 15);
  int t = threadIdx.x;                // position f
  for (int i = t; i < 320; i += 256)  // FIX: 320 entries > 256 threads
    s_l[i] = sproto[(i >> 6) * 512 + gc * 64 + (i & 63)];
  __syncthreads();
  const _Float16* ub = u + (size_t)b * SAMP + (size_t)gc * 64 * HWP;
  float dot[5] = {0, 0, 0, 0, 0}, qq = 0.f;
#pragma unroll 8
  for (int c = 0; c < 64; c++) {
    float v = (float)ub[c * HWP + t];
    qq += v * v;
#pragma unroll
    for (int m = 0; m < 5; m++) dot[m] += v * s_l[m * 64 + c];
  }
  float* pp = part + (((size_t)n * 8 + gc) * 256 + t) * 6;
  pp[0] = dot[0]; pp[1] = dot[1]; pp[2] = dot[2];
  pp[3] = dot[3]; pp[4] = dot[4]; pp[5] = qq;
}

// ---- K4b: combine partials -> cosine -> softmax(5) -> spatial mean ----
__global__ __launch_bounds__(256) void k_comb(const float* __restrict__ part,
                                             const float* __restrict__ pref,
                                             float* __restrict__ out) {
  int n = blockIdx.x, t = threadIdx.x;   // t = position f
  float dot[5] = {0, 0, 0, 0, 0}, qq = 0.f;
#pragma unroll
  for (int gc = 0; gc < 8; gc++) {
    const float* pp = part + (((size_t)n * 8 + gc) * 256 + t) * 6;
    dot[0] += pp[0]; dot[1] += pp[1]; dot[2] += pp[2];
    dot[3] += pp[3]; dot[4] += pp[4]; qq += pp[5];
  }
  float iqn = 1.0f / fmaxf(sqrtf(qq), 1e-20f);
  float sc[5], mx = -1e30f;
#pragma unroll
  for (int m = 0; m < 5; m++) { sc[m] = dot[m] * pref[m] * iqn; mx = fmaxf(mx, sc[m]); }
  float p[5], ssum = 0.f;
#pragma unroll
  for (int m = 0; m < 5; m++) { p[m] = __expf(sc[m] - mx); ssum += p[m]; }
  float rr = 1.0f / ssum;
#pragma unroll
  for (int m = 0; m < 5; m++) {
    float v = p[m] * rr;
#pragma unroll
    for (int off = 32; off; off >>= 1) v += __shfl_down(v, off, 64);
    p[m] = v;   // lane0 of each wave holds wave sum
  }
  __shared__ float rs[4][5];
  if ((t & 63) == 0) {
#pragma unroll
    for (int m = 0; m < 5; m++) rs[t >> 6][m] = p[m];
  }
  __syncthreads();
  if (t < 5) out[n * 5 + t] =
      (rs[0][t] + rs[1][t] + rs[2][t] + rs[3][t]) * (1.0f / 256.0f);
}

extern "C" void kernel_launch(void* const* d_in, const int* in_sizes, int n_in,
                              void* d_out, int out_size, void* d_ws, size_t ws_size,
                              hipStream_t stream) {
  const float* x    = (const float*)d_in[0];   // (100,512,16,16)
  const float* W    = (const float*)d_in[1];   // (512,512)
  const float* bias = (const float*)d_in[2];   // (512,)
  float* out = (float*)d_out;                  // (75,5) fp32

  char* ws = (char*)d_ws;
  _Float16* xh     = (_Float16*)(ws + 0);          // 26,214,400 B (dead after gemm)
  float*    part   = (float*)   (ws + 0);          //  2,764,800 B (aliases xh)
  _Float16* Wh     = (_Float16*)(ws + 26214400);   //    524,288 B
  _Float16* u      = (_Float16*)(ws + 26738688);   // 26,214,400 B  u = x*exp(logit)
  float*    denom  = (float*)   (ws + 52953088);   //        512 B
  float*    sproto = (float*)   (ws + 52953600);   //     10,240 B
  float*    pref   = (float*)   (ws + 52963840);   //        512 B

  hipMemsetAsync(denom, 0, 512, stream);
  k_txpose <<<3200, 256, 0, stream>>>(x, xh);
  k_convw  <<<256,  256, 0, stream>>>(W, Wh);
  k_gemm   <<<800,  256, 0, stream>>>(Wh, xh, bias, u, denom);
  k_proto  <<<2560, 256, 0, stream>>>(u, denom, sproto);
  k_sn     <<<5,    256, 0, stream>>>(sproto, pref);
  k_part   <<<600,  256, 0, stream>>>(u, sproto, part);
  k_comb   <<<75,   256, 0, stream>>>(part, pref, out);
}